// Round 10
// baseline (176.790 us; speedup 1.0000x reference)
//
#include <hip/hip_runtime.h>
#include <hip/hip_bf16.h>
#include <stdint.h>

#define B_ 1024
#define N_ 128
#define D_ 128
#define H_ 256
#define L_ 64
#define INF_ 0x3FFFFFFF

typedef __attribute__((ext_vector_type(8))) short bf16x8;
typedef __attribute__((ext_vector_type(4))) float f32x4;
typedef __attribute__((ext_vector_type(4))) uint32_t u32x4;
typedef __attribute__((ext_vector_type(2))) uint32_t u32x2;

__device__ __forceinline__ uint32_t pack2(float a, float b) {
    __hip_bfloat162 h = __float22bfloat162_rn(make_float2(a, b));
    uint32_t u;
    __builtin_memcpy(&u, &h, 4);
    return u;
}

// ---------------- weight prep: fragment-linear bf16 layouts in ws ----------------
__global__ void prep_weights(const float* __restrict__ W1, const float* __restrict__ W2,
                             uint16_t* __restrict__ ws) {
    int t = blockIdx.x * 256 + threadIdx.x;
    if (t < 4096) {                       // W1T A-frags: A[m=h][k=f]
        int lane = t & 63, fkb = t >> 6;
        int tm = fkb >> 2, kb = fkb & 3;
        int h  = tm * 16 + (lane & 15);
        int k0 = kb * 32 + (lane >> 4) * 8;
        u32x4 w;
        #pragma unroll
        for (int p = 0; p < 4; ++p)
            w[p] = pack2(W1[(k0 + 2*p) * H_ + h], W1[(k0 + 2*p + 1) * H_ + h]);
        *reinterpret_cast<u32x4*>(&ws[t * 8]) = w;
    } else if (t < 12288) {               // W2 B-frags: B[k][n]
        int t2 = t - 4096;
        int lane = t2 & 63, g = t2 >> 6;
        int tn = g >> 3, kb = g & 7;
        int n  = tn * 16 + (lane & 15);
        int k0 = kb * 32 + (lane >> 4) * 8;
        u32x4 w;
        #pragma unroll
        for (int p = 0; p < 4; ++p)
            w[p] = pack2(W2[(k0 + 2*p) * H_ + n], W2[(k0 + 2*p + 1) * H_ + n]);
        *reinterpret_cast<u32x4*>(&ws[32768 + t2 * 8]) = w;
    }
}

// ---------------- fused kernel: 1 block/graph, 256 thr, bulk phases, 2 blocks/CU ----------------
__global__ __launch_bounds__(256) void fused_kernel(
    const float* __restrict__ x, const float* __restrict__ adj,
    const uint16_t* __restrict__ ws,
    const float* __restrict__ b1g, const float* __restrict__ b2g,
    const float* __restrict__ Wmu, const float* __restrict__ bmu,
    const float* __restrict__ Wlv, const float* __restrict__ blv,
    float* __restrict__ out)
{
    // buf 64 KB (32768 u16):
    //   phase BFS : overlay at u16[16384..): adjm/order/parent/key
    //   phase agg1: xa frags at [0,16384), f32 x-chunk at [16384,24576)
    //   phase m1  : reads xa, then h1 frags occupy [0,32768)
    //   phase m2  : reads h1, then M2 frags occupy [0,32768)
    //   phase agg2: reads M2
    __shared__ __align__(16) uint16_t buf[32768];
    __shared__ __align__(16) uint32_t tnbr[128][4];
    __shared__ float    s_inv[128];
    __shared__ float    s_wm[128];
    __shared__ float    s_g[256];
    __shared__ float    s_p[256];
    __shared__ uint32_t visw[4], actw[4], newlyw[4];
    __shared__ int      s_root;

    uint32_t* adjm     = reinterpret_cast<uint32_t*>(buf) + 8192;   // [512]
    int*      s_order  = reinterpret_cast<int*>(buf) + 8704;        // [128]
    int*      s_parent = reinterpret_cast<int*>(buf) + 8832;        // [128]
    int*      s_key    = reinterpret_cast<int*>(buf) + 8960;        // [128]

    const int tid  = threadIdx.x;
    const int b    = blockIdx.x;
    const int wid  = tid >> 6;          // 0..3
    const int lane = tid & 63;
    const int l15  = lane & 15;
    const int q    = lane >> 4;

    const float4* xg4 = reinterpret_cast<const float4*>(x + (size_t)b * N_ * D_);
    const float*  ag  = adj + (size_t)b * N_ * N_;

    // ---------- prefetch x chunk 0 (hides under adj + BFS) ----------
    const int prow = tid >> 3;               // base row (i adds 32)
    const int pcol = tid & 7;
    const int pswz = pcol ^ (prow & 7);
    float4 pf[4];
    #pragma unroll
    for (int i = 0; i < 4; ++i)
        pf[i] = xg4[(prow + i * 32) * 32 + pcol];

    // ---------- init + adj -> bitmasks ----------
    if (tid < 128) { s_order[tid] = INF_; s_parent[tid] = 0; }
    if (tid < 4)   { visw[tid] = 0u; actw[tid] = 0u; }
    if (tid == 0)  { s_root = 128; }
    {
        const int v = tid >> 1, hf = tid & 1;
        const float4* ag4 = reinterpret_cast<const float4*>(ag + v * N_ + hf * 64);
        uint32_t w0 = 0, w1 = 0;
        #pragma unroll
        for (int i = 0; i < 16; ++i) {
            float4 f = ag4[i];
            uint32_t bs = (f.x > 0.5f ? 1u : 0u) | (f.y > 0.5f ? 2u : 0u) |
                          (f.z > 0.5f ? 4u : 0u) | (f.w > 0.5f ? 8u : 0u);
            int base = i * 4;
            if (base < 32) w0 |= bs << base; else w1 |= bs << (base - 32);
        }
        adjm[v * 4 + hf * 2]     = w0;
        adjm[v * 4 + hf * 2 + 1] = w1;
    }
    __syncthreads();

    // ---------- active nodes + root ----------
    if (tid < 128) {
        uint32_t any = adjm[tid*4+0] | adjm[tid*4+1] | adjm[tid*4+2] | adjm[tid*4+3];
        if (any) {
            atomicMin(&s_root, tid);
            atomicOr(&actw[tid >> 5], 1u << (tid & 31));
        }
    }
    __syncthreads();
    int counter = 0;
    if (s_root < 128) {
        counter = 1;
        if (tid == 0) {
            s_order[s_root] = 0;
            visw[s_root >> 5] = 1u << (s_root & 31);
        }
    }
    __syncthreads();

    // ---------- level-synchronous FIFO BFS ----------
    for (int step = 0; step < N_ - 1; ++step) {
        if (tid < 4) newlyw[tid] = 0u;
        __syncthreads();
        int newly = 0, po = INF_, par = 0;
        if (tid < 128 && s_order[tid] >= INF_) {
            #pragma unroll
            for (int w = 0; w < 4; ++w) {
                uint32_t m = adjm[tid * 4 + w] & visw[w];
                while (m) {
                    int u = (w << 5) + __ffs(m) - 1; m &= m - 1;
                    int o = s_order[u];
                    if (o < po) { po = o; par = u; }
                }
            }
            newly = (po < INF_);
            if (newly) {
                s_key[tid] = po * N_ + tid;
                atomicOr(&newlyw[tid >> 5], 1u << (tid & 31));
            }
        }
        __syncthreads();
        int myk = newly ? po * N_ + tid : 0x7FFFFFFF;
        int cnt = 0, rank = 0;
        #pragma unroll
        for (int w = 0; w < 4; ++w) {
            uint32_t m = newlyw[w];
            cnt += __popc(m);
            while (m) {
                int u = (w << 5) + __ffs(m) - 1; m &= m - 1;
                rank += (s_key[u] < myk);
            }
        }
        if (newly) {
            s_order[tid]  = counter + rank;
            s_parent[tid] = par;
            atomicOr(&visw[tid >> 5], 1u << (tid & 31));
        }
        counter += cnt;
        __syncthreads();
        if (cnt == 0) break;
    }

    // ---------- tree masks + degrees + pool weights ----------
    if (tid < 128) { tnbr[tid][0] = 0; tnbr[tid][1] = 0; tnbr[tid][2] = 0; tnbr[tid][3] = 0; }
    __syncthreads();
    if (tid < 128 && s_order[tid] > 0 && s_order[tid] < INF_) {
        int p = s_parent[tid];
        atomicOr(&tnbr[tid][p >> 5], 1u << (p & 31));
        atomicOr(&tnbr[p][tid >> 5], 1u << (tid & 31));
    }
    __syncthreads();
    if (tid < 128) {
        int d = 1 + __popc(tnbr[tid][0]) + __popc(tnbr[tid][1]) +
                    __popc(tnbr[tid][2]) + __popc(tnbr[tid][3]);
        int num = __popc(actw[0]) + __popc(actw[1]) + __popc(actw[2]) + __popc(actw[3]);
        int act = (actw[tid >> 5] >> (tid & 31)) & 1;
        s_inv[tid] = 1.0f / (float)d;
        s_wm[tid]  = act ? (1.0f / (float)(num > 0 ? num : 1)) : 0.0f;
    }
    __syncthreads();   // BFS overlay dead; agg1 chunk region may overwrite it

    // ---------- agg1: 4 rounds {stage f32 chunk -> gather -> xa frags at buf[0..)} ----------
    float4* chunkF4 = reinterpret_cast<float4*>(buf + 16384);   // 16 KB slice
    const int gv = tid >> 1, gp2 = tid & 1;     // row, 16-feat half

    for (int r = 0; r < 4; ++r) {
        #pragma unroll
        for (int i = 0; i < 4; ++i)
            chunkF4[(prow + i * 32) * 8 + pswz] = pf[i];
        if (r < 3) {
            #pragma unroll
            for (int i = 0; i < 4; ++i)
                pf[i] = xg4[(prow + i * 32) * 32 + (r + 1) * 8 + pcol];
        }
        __syncthreads();
        float acc[16];
        #pragma unroll
        for (int k = 0; k < 4; ++k) {
            float4 a = chunkF4[gv * 8 + ((gp2 * 4 + k) ^ (gv & 7))];
            acc[k*4+0] = a.x; acc[k*4+1] = a.y; acc[k*4+2] = a.z; acc[k*4+3] = a.w;
        }
        #pragma unroll
        for (int w = 0; w < 4; ++w) {
            uint32_t m = tnbr[gv][w];
            while (m) {
                int u = (w << 5) + __ffs(m) - 1; m &= m - 1;
                #pragma unroll
                for (int k = 0; k < 4; ++k) {
                    float4 n = chunkF4[u * 8 + ((gp2 * 4 + k) ^ (u & 7))];
                    acc[k*4+0] += n.x; acc[k*4+1] += n.y;
                    acc[k*4+2] += n.z; acc[k*4+3] += n.w;
                }
            }
        }
        const float inv = s_inv[gv];
        #pragma unroll
        for (int gg = 0; gg < 2; ++gg) {
            const int gp = gp2 * 2 + gg;
            u32x4 wv;
            wv[0] = pack2(acc[gg*8+0] * inv, acc[gg*8+1] * inv);
            wv[1] = pack2(acc[gg*8+2] * inv, acc[gg*8+3] * inv);
            wv[2] = pack2(acc[gg*8+4] * inv, acc[gg*8+5] * inv);
            wv[3] = pack2(acc[gg*8+6] * inv, acc[gg*8+7] * inv);
            *reinterpret_cast<u32x4*>(
                &buf[(((gv >> 4) * 4 + r) * 64 + gp * 16 + (gv & 15)) * 8]) = wv;
        }
        __syncthreads();
    }

    const bf16x8* wsA = reinterpret_cast<const bf16x8*>(ws);
    const bf16x8* wsB = reinterpret_cast<const bf16x8*>(ws + 32768);

    // ---------- m1 bulk: h1^T = W1^T @ xa^T; acc held across barrier, then write h1 ----------
    {
        f32x4 acc1[4][8];
        #pragma unroll
        for (int j = 0; j < 4; ++j)
            #pragma unroll
            for (int t = 0; t < 8; ++t) acc1[j][t] = (f32x4){0.f, 0.f, 0.f, 0.f};
        for (int kb = 0; kb < 4; ++kb) {
            bf16x8 afr[4], bfr[8];
            #pragma unroll
            for (int j = 0; j < 4; ++j)
                afr[j] = wsA[((wid * 4 + j) * 4 + kb) * 64 + lane];
            #pragma unroll
            for (int t = 0; t < 8; ++t)
                bfr[t] = *reinterpret_cast<const bf16x8*>(
                    &buf[((t * 4 + kb) * 64 + lane) * 8]);
            #pragma unroll
            for (int j = 0; j < 4; ++j)
                #pragma unroll
                for (int t = 0; t < 8; ++t)
                    acc1[j][t] = __builtin_amdgcn_mfma_f32_16x16x32_bf16(
                        afr[j], bfr[t], acc1[j][t], 0, 0, 0);
        }
        __syncthreads();   // all xa reads done before h1 overwrites buf
        #pragma unroll
        for (int j = 0; j < 4; ++j) {
            int tm = wid * 4 + j;
            int m0 = tm * 16 + q * 4;
            f32x4 bb = *reinterpret_cast<const f32x4*>(b1g + m0);
            int kbh = tm >> 1;
            int sl  = l15 + 16 * ((2 * tm + (q >> 1)) & 3);
            #pragma unroll
            for (int t = 0; t < 8; ++t) {
                f32x4 v = acc1[j][t];
                float v0 = fmaxf(v[0] + bb[0], 0.f), v1 = fmaxf(v[1] + bb[1], 0.f);
                float v2 = fmaxf(v[2] + bb[2], 0.f), v3 = fmaxf(v[3] + bb[3], 0.f);
                u32x2 w; w[0] = pack2(v0, v1); w[1] = pack2(v2, v3);
                *reinterpret_cast<u32x2*>(
                    &buf[((t * 8 + kbh) * 64 + sl) * 8 + (q & 1) * 4]) = w;
            }
        }
    }
    __syncthreads();

    // ---------- m2 bulk: M2 = h1 @ W2; acc across barrier, write M2 frags ----------
    {
        f32x4 acc2[8][4];
        #pragma unroll
        for (int tm = 0; tm < 8; ++tm)
            #pragma unroll
            for (int j = 0; j < 4; ++j) acc2[tm][j] = (f32x4){0.f, 0.f, 0.f, 0.f};
        for (int kb = 0; kb < 8; ++kb) {
            bf16x8 a2[8], bfr[4];
            #pragma unroll
            for (int tm = 0; tm < 8; ++tm)
                a2[tm] = *reinterpret_cast<const bf16x8*>(
                    &buf[((tm * 8 + kb) * 64 + lane) * 8]);
            #pragma unroll
            for (int j = 0; j < 4; ++j)
                bfr[j] = wsB[((wid * 4 + j) * 8 + kb) * 64 + lane];
            #pragma unroll
            for (int tm = 0; tm < 8; ++tm)
                #pragma unroll
                for (int j = 0; j < 4; ++j)
                    acc2[tm][j] = __builtin_amdgcn_mfma_f32_16x16x32_bf16(
                        a2[tm], bfr[j], acc2[tm][j], 0, 0, 0);
        }
        __syncthreads();   // all h1 reads done
        #pragma unroll
        for (int tm = 0; tm < 8; ++tm) {
            int kbh = tm >> 1;
            int sl  = l15 + 16 * ((2 * tm + (q >> 1)) & 3);
            #pragma unroll
            for (int j = 0; j < 4; ++j) {
                int tn = wid * 4 + j;
                f32x4 v = acc2[tm][j];
                u32x2 w; w[0] = pack2(v[0], v[1]); w[1] = pack2(v[2], v[3]);
                *reinterpret_cast<u32x2*>(
                    &buf[((tn * 4 + kbh) * 64 + sl) * 8 + (q & 1) * 4]) = w;
            }
        }
    }
    __syncthreads();

    // ---------- agg2 bulk via MFMA (A = T-hat from bitmasks) + fused pool ----------
    {
        f32x4 acc3[8][4];
        #pragma unroll
        for (int tm = 0; tm < 8; ++tm)
            #pragma unroll
            for (int j = 0; j < 4; ++j) acc3[tm][j] = (f32x4){0.f, 0.f, 0.f, 0.f};
        for (int kb = 0; kb < 4; ++kb) {
            bf16x8 a3[8], bfr[4];
            #pragma unroll
            for (int tm = 0; tm < 8; ++tm) {
                int v = tm * 16 + l15;
                uint32_t word = tnbr[v][kb];
                uint32_t by = (word >> (q * 8)) & 0xFFu;
                if ((v >> 3) == kb * 4 + q) by |= 1u << (v & 7);
                u32x4 pm;
                #pragma unroll
                for (int pp = 0; pp < 4; ++pp)
                    pm[pp] = (((by >> (2 * pp)) & 1u) ? 0x3F80u : 0u) |
                             (((by >> (2 * pp + 1)) & 1u) ? 0x3F800000u : 0u);
                a3[tm] = __builtin_bit_cast(bf16x8, pm);
            }
            #pragma unroll
            for (int j = 0; j < 4; ++j)
                bfr[j] = *reinterpret_cast<const bf16x8*>(
                    &buf[(((wid * 4 + j) * 4 + kb) * 64 + lane) * 8]);
            #pragma unroll
            for (int tm = 0; tm < 8; ++tm)
                #pragma unroll
                for (int j = 0; j < 4; ++j)
                    acc3[tm][j] = __builtin_amdgcn_mfma_f32_16x16x32_bf16(
                        a3[tm], bfr[j], acc3[tm][j], 0, 0, 0);
        }
        float ps[4] = {0.f, 0.f, 0.f, 0.f};
        #pragma unroll
        for (int tm = 0; tm < 8; ++tm) {
            int v0 = tm * 16 + q * 4;
            f32x4 iv = *reinterpret_cast<const f32x4*>(&s_inv[v0]);
            f32x4 wm = *reinterpret_cast<const f32x4*>(&s_wm[v0]);
            #pragma unroll
            for (int j = 0; j < 4; ++j) {
                float bc = b2g[(wid * 4 + j) * 16 + l15];
                f32x4 a = acc3[tm][j];
                #pragma unroll
                for (int r = 0; r < 4; ++r)
                    ps[j] += fmaxf(fmaf(a[r], iv[r], bc), 0.f) * wm[r];
            }
        }
        #pragma unroll
        for (int j = 0; j < 4; ++j) {
            ps[j] += __shfl_xor(ps[j], 16);
            ps[j] += __shfl_xor(ps[j], 32);
        }
        if (q == 0) {
            #pragma unroll
            for (int j = 0; j < 4; ++j)
                s_g[(wid * 4 + j) * 16 + l15] = ps[j];
        }
    }
    __syncthreads();

    // ---------- heads inline: out = g @ {Wmu,Wlv} + bias (2 thr / output) ----------
    {
        const int oi = tid & 127, part = tid >> 7;
        const int which = oi >> 6, l = oi & 63;
        const float* W = which ? Wlv : Wmu;
        float acc = 0.f;
        const int c0 = part * 128;
        #pragma unroll 8
        for (int cc = 0; cc < 128; ++cc)
            acc = fmaf(s_g[c0 + cc], W[(c0 + cc) * L_ + l], acc);
        s_p[part * 128 + oi] = acc;
        __syncthreads();
        if (tid < 128) {
            const int w2 = tid >> 6, l2 = tid & 63;
            float r = s_p[tid] + s_p[128 + tid];
            r += w2 ? blv[l2] : bmu[l2];
            out[(size_t)w2 * B_ * L_ + (size_t)b * L_ + l2] = r;
        }
    }
}

extern "C" void kernel_launch(void* const* d_in, const int* in_sizes, int n_in,
                              void* d_out, int out_size, void* d_ws, size_t ws_size,
                              hipStream_t stream) {
    const float* x   = (const float*)d_in[0];
    const float* adj = (const float*)d_in[1];
    const float* W1  = (const float*)d_in[2];
    const float* b1  = (const float*)d_in[3];
    const float* W2  = (const float*)d_in[4];
    const float* b2  = (const float*)d_in[5];
    const float* Wmu = (const float*)d_in[6];
    const float* bmu = (const float*)d_in[7];
    const float* Wlv = (const float*)d_in[8];
    const float* blv = (const float*)d_in[9];
    float* out = (float*)d_out;
    uint16_t* ws = (uint16_t*)d_ws;

    hipLaunchKernelGGL(prep_weights, dim3(48), dim3(256), 0, stream, W1, W2, ws);
    hipLaunchKernelGGL(fused_kernel, dim3(B_), dim3(256), 0, stream,
                       x, adj, ws, b1, b2, Wmu, bmu, Wlv, blv, out);
}